// Round 2
// baseline (563.571 us; speedup 1.0000x reference)
//
#include <hip/hip_runtime.h>

// Problem constants (fixed by the reference)
#define BTOT 4096
#define TB   512
#define BD   8
#define BSL  16    // MFMA tile M (R6 lesson: BSL=8 duplicates work chip-wide)

// LDS element map (uint16 elements, 2 B), k-major block layout:
//   A-tile element (row,k) at blk*128 + row*8 + (k&7), blk = k>>3
//   -> lane (q,ln)'s A-frag (row=ln, k=ki*32+q*8+j) = 16 contiguous bytes
//      at (ki*4+q)*128 + ln*8  => ds_read_b128, conflict-free per 8-lane group.
// A0 (h0, K=64): parity p at p*1024                      (els 0..2047)
// A1 (h1, K=64): parity p at 2048 + p*1024               (els 2048..4095)
// ZERO block (always 0, x-frag source for q>0 lanes):    (els 4096..4223)
// XB x chunks (64 t x 16 rows x 8 d, double-buffered):   (els 8192..24575)
#define A0TOG  1024
#define A1BASE 2048
#define A1TOG  1024
#define ZBASE  4096
#define XBASE  8192
#define NLDS   24576   // 48 KiB

typedef __attribute__((ext_vector_type(8))) short  short8;  // MFMA A/B frag
typedef __attribute__((ext_vector_type(4))) float  f32x4;   // MFMA C/D frag

#define MFMA16 __builtin_amdgcn_mfma_f32_16x16x32_bf16

// Raw barrier: wait only LDS ops (ds_write visibility), leave vmcnt
// outstanding so the ph48 global x-prefetch hides across ~14 barriers.
#define BAR() asm volatile("s_waitcnt lgkmcnt(0)\n\ts_barrier" ::: "memory")

static __device__ __forceinline__ unsigned short f2bf(float f) {
    unsigned u = __float_as_uint(f);
    u += 0x7fffu + ((u >> 16) & 1u);
    return (unsigned short)(u >> 16);
}
static __device__ __forceinline__ float bf2f(unsigned short h) {
    return __uint_as_float(((unsigned)h) << 16);
}
static __device__ __forceinline__ unsigned pkbf(float a, float b) {
    unsigned r;  // gfx950 HW packed f32->bf16 (RNE); dest must be VGPR
    asm("v_cvt_pk_bf16_f32 %0, %1, %2" : "=v"(r) : "v"(a), "v"(b));
    return r;
}

// Fast reciprocal OFF the trans pipe: bit-hack seed (~3.4% err) + 2 Newton
// iters -> ~1e-6 rel err (better than bf16 4e-3 quantization). 5 VALU ops
// on the VALU pipe instead of 16 cy on the saturated trans pipe.
// Valid for d in (1, 2^30): always true here (all denominators are
// products of (1+2^z) terms, z bounded by gate pre-activations).
static __device__ __forceinline__ float fastrcp(float d) {
    float y = __uint_as_float(0x7EF311C3u - __float_as_uint(d));
    y = y * (2.0f - d * y);
    y = y * (2.0f - d * y);
    return y;
}

// One LSTM unit (one row of one lane's f32x4 accumulators).
// 5 exp2 on trans pipe + 2 fastrcp on VALU pipe (was 7 trans ops).
// Pre-folded scales: i,f,o rows x -log2(e); g row x 2*log2(e).
//   c' = f*c + i*g = [c*Ai*Ag + Af*(eg-1)] / (Af*Ai*Ag)
//   h  = o*tanh(c') = (ec-1) / (Ao*(ec+1)),  ec = 2^(2*log2(e)*c')
static __device__ __forceinline__ float gate_row(
    float zi, float zf, float zg, float zo, float& c)
{
    const float ei = __builtin_amdgcn_exp2f(zi);
    const float ef = __builtin_amdgcn_exp2f(zf);
    const float eg = __builtin_amdgcn_exp2f(zg);
    const float eo = __builtin_amdgcn_exp2f(zo);
    const float Ai = 1.f + ei, Af = 1.f + ef, Ag = 1.f + eg, Ao = 1.f + eo;
    const float P     = Ai * Ag;
    const float numer = c * P + Af * (eg - 1.f);
    const float rD    = fastrcp(Af * P);
    c = numer * rD;
    const float ec = __builtin_amdgcn_exp2f(2.88539008f * c);
    const float rH = fastrcp(Ao * (ec + 1.f));
    return (ec - 1.f) * rH;
}

static __device__ __forceinline__ void gates4(
    const f32x4 ai, const f32x4 af, const f32x4 ag, const f32x4 ao,
    float cc[4], unsigned hp[2])
{
    float h[4];
    #pragma unroll
    for (int r = 0; r < 4; ++r)
        h[r] = gate_row(ai[r], af[r], ag[r], ao[r], cc[r]);
    hp[0] = pkbf(h[0], h[1]); hp[1] = pkbf(h[2], h[3]);
}

// MERGED-WAVE + PIPE-INTERLEAVE DESIGN: 4 waves/block, each wave owns 16
// hidden cols for BOTH layers. R1 post-mortem: step time ~2170 cy matched
// [MFMA 543] + [trans 896] + [VALU] + [serial edges] run SEQUENTIALLY.
// This round: (a) fastrcp moves 2/7 of trans ops to the VALU pipe;
// (b) steady-state body interleaves L1's 16 MFMAs with gates0's 4 rows at
// source level so the matrix pipe runs UNDER the trans segment.
__global__ __launch_bounds__(256, 1) void lstm2_fused(
    const float* __restrict__ x,
    const float* __restrict__ Wih0, const float* __restrict__ Whh0,
    const float* __restrict__ bih0, const float* __restrict__ bhh0,
    const float* __restrict__ Wih1, const float* __restrict__ Whh1,
    const float* __restrict__ bih1, const float* __restrict__ bhh1,
    const float* __restrict__ Wfc,  const float* __restrict__ bfc,
    float* __restrict__ out)
{
    __shared__ __align__(16) unsigned short lds16[NLDS];

    const int tid  = threadIdx.x;
    const int wid  = tid >> 6;           // 4 waves; wave g = cols 16g..16g+15
    const int lane = tid & 63;
    const int q    = lane >> 4;
    const int ln   = lane & 15;
    const int rb   = blockIdx.x * BSL;
    const int jc   = wid * 16 + ln;      // hidden col this lane owns (both layers)

    const float SCI = -1.44269504f;
    const float SCG =  2.88539008f;

    // ---- Weight fragments -> registers (both layers), bf16, scales folded ----
    short8 Bf0[4][3];                    // L0: k 0..63 = Whh0, 64..71 = Wih0
    short8 Bf1[4][4];                    // L1: k 0..63 = Wih1, 64..127 = Whh1
    #pragma unroll
    for (int G = 0; G < 4; ++G) {
        const int n = G * 64 + jc;
        const float sc = (G == 2) ? SCG : SCI;
        #pragma unroll
        for (int ki = 0; ki < 3; ++ki) {
            union { unsigned short u[8]; short8 v; } t;
            #pragma unroll
            for (int j = 0; j < 8; ++j) {
                const int k = ki * 32 + q * 8 + j;
                float wv = 0.0f;
                if (k < 64)      wv = Whh0[n * 64 + k];
                else if (k < 72) wv = Wih0[n * 8 + (k - 64)];
                t.u[j] = f2bf(sc * wv);
            }
            Bf0[G][ki] = t.v;
        }
        #pragma unroll
        for (int ki = 0; ki < 4; ++ki) {
            union { unsigned short u[8]; short8 v; } t;
            #pragma unroll
            for (int j = 0; j < 8; ++j) {
                const int k = ki * 32 + q * 8 + j;
                const float wv = (k < 64) ? Wih1[n * 64 + k]
                                          : Whh1[n * 64 + (k - 64)];
                t.u[j] = f2bf(sc * wv);
            }
            Bf1[G][ki] = t.v;
        }
    }
    f32x4 bias0[4], bias1[4];            // bias as persistent MFMA C-operand
    #pragma unroll
    for (int G = 0; G < 4; ++G) {
        const int n = G * 64 + jc;
        const float sc = (G == 2) ? SCG : SCI;
        const float b0 = sc * (bih0[n] + bhh0[n]);
        const float b1 = sc * (bih1[n] + bhh1[n]);
        bias0[G] = (f32x4){b0, b0, b0, b0};
        bias1[G] = (f32x4){b1, b1, b1, b1};
    }

    // ---- Prologue: zero A0/A1/ZERO, stage x chunk 0 ----
    {
        unsigned* z = (unsigned*)lds16;   // els 0..4223 = 2112 dwords
        #pragma unroll
        for (int i = 0; i < 9; ++i) {
            const int id = tid + i * 256;
            if (id < 2112) z[id] = 0;
        }
    }
    const int srow = tid >> 4, su = tid & 15;  // stager: 32 floats/thread
    {
        const float* gp = x + (size_t)(rb + srow) * (TB * BD) + su * 32;
        float4 v[8];
        #pragma unroll
        for (int i = 0; i < 8; ++i) v[i] = ((const float4*)gp)[i];
        #pragma unroll
        for (int tt = 0; tt < 4; ++tt) {
            uint4 s;
            s.x = pkbf(v[2*tt].x,   v[2*tt].y);   s.y = pkbf(v[2*tt].z,   v[2*tt].w);
            s.z = pkbf(v[2*tt+1].x, v[2*tt+1].y); s.w = pkbf(v[2*tt+1].z, v[2*tt+1].w);
            const int el = XBASE + (su * 4 + tt) * 128 + srow * 8;
            *(uint4*)(lds16 + el) = s;
        }
    }
    __syncthreads();

    // ---- Hoisted ping-pong pointers (element indices), XOR-toggled ----
    const int rbase = q * 128 + ln * 8;                    // A-frag read base
    const int wb    = (jc >> 3) * 128 + q * 32 + (jc & 7); // h-write base
    const int ln8   = ln * 8;
    const int zaddr = ZBASE + ln8;       // q>0 x-frag source (always zero)
    int rdA  = rbase;                    // h0(t-1): read by BOTH layers
    int wr0  = A0TOG + wb;               // h0(t) -> other parity
    int rdH1 = A1BASE + rbase;           // h1(t1-1)
    int wrH1 = A1BASE + A1TOG + wb;      // h1(t1) -> other parity

    float cc0[4] = {0.f, 0.f, 0.f, 0.f};
    float cc1[4] = {0.f, 0.f, 0.f, 0.f};
    float4 px[8];                        // x-chunk global prefetch registers

    // ---- Peeled it=0: L0 only (h0(-1)=h1(-1)=0) ----
    {
        const short8 a0 = *(const short8*)(lds16 + rdA);
        const short8 a1 = *(const short8*)(lds16 + rdA + 512);
        const int xaddr = (q == 0) ? (XBASE + 0 + ln8) : zaddr;
        const short8 a2 = *(const short8*)(lds16 + xaddr);
        f32x4 ai = MFMA16(a0, Bf0[0][0], bias0[0], 0, 0, 0);
        f32x4 af = MFMA16(a0, Bf0[1][0], bias0[1], 0, 0, 0);
        f32x4 ag = MFMA16(a0, Bf0[2][0], bias0[2], 0, 0, 0);
        f32x4 ao = MFMA16(a0, Bf0[3][0], bias0[3], 0, 0, 0);
        ai = MFMA16(a1, Bf0[0][1], ai, 0, 0, 0);
        af = MFMA16(a1, Bf0[1][1], af, 0, 0, 0);
        ag = MFMA16(a1, Bf0[2][1], ag, 0, 0, 0);
        ao = MFMA16(a1, Bf0[3][1], ao, 0, 0, 0);
        ai = MFMA16(a2, Bf0[0][2], ai, 0, 0, 0);
        af = MFMA16(a2, Bf0[1][2], af, 0, 0, 0);
        ag = MFMA16(a2, Bf0[2][2], ag, 0, 0, 0);
        ao = MFMA16(a2, Bf0[3][2], ao, 0, 0, 0);
        unsigned hp[2];
        gates4(ai, af, ag, ao, cc0, hp);
        lds16[wr0]      = (unsigned short)hp[0];
        lds16[wr0 + 8]  = (unsigned short)(hp[0] >> 16);
        lds16[wr0 + 16] = (unsigned short)hp[1];
        lds16[wr0 + 24] = (unsigned short)(hp[1] >> 16);
        BAR();
        rdA ^= A0TOG; wr0 ^= A0TOG; rdH1 ^= A1TOG; wrH1 ^= A1TOG;
    }

    // ---- Steady state it=1..TB-1: interleaved pipes, both layers ----
    for (int it = 1; it < TB; ++it) {
        const int ph = it & 63;
        // Shared reads first (post-barrier critical path): h0(it-1) feeds
        // L0 recurrence AND L1 input; h1(it-2) feeds L1 recurrence.
        const short8 a0 = *(const short8*)(lds16 + rdA);
        const short8 a1 = *(const short8*)(lds16 + rdA + 512);
        const short8 b2 = *(const short8*)(lds16 + rdH1);        // h1 k 0..31
        const short8 b3 = *(const short8*)(lds16 + rdH1 + 512);  // h1 k 32..63
        const int xaddr = (q == 0) ? (XBASE + ((it & 127) << 7) + ln8) : zaddr;
        const short8 a2 = *(const short8*)(lds16 + xaddr);

        if (ph == 48 && it + 16 < TB) {  // prefetch next chunk -> regs
            const int t0 = (it & ~63) + 64;
            const float* gp = x + (size_t)(rb + srow) * (TB * BD) + t0 * BD + su * 32;
            #pragma unroll
            for (int i = 0; i < 8; ++i) px[i] = ((const float4*)gp)[i];
        }
        if (ph == 62 && it + 2 < TB) {   // pack + write to OTHER XB buffer
            const int t0 = (it & ~63) + 64;
            #pragma unroll
            for (int tt = 0; tt < 4; ++tt) {
                uint4 s;
                s.x = pkbf(px[2*tt].x,   px[2*tt].y);   s.y = pkbf(px[2*tt].z,   px[2*tt].w);
                s.z = pkbf(px[2*tt+1].x, px[2*tt+1].y); s.w = pkbf(px[2*tt+1].z, px[2*tt+1].w);
                const int el = XBASE + ((t0 + su * 4 + tt) & 127) * 128 + srow * 8;
                *(uint4*)(lds16 + el) = s;
            }
        }

        // L0 MFMAs (step t = it) — gates0 needs all 12 complete
        f32x4 ai0 = MFMA16(a0, Bf0[0][0], bias0[0], 0, 0, 0);
        f32x4 af0 = MFMA16(a0, Bf0[1][0], bias0[1], 0, 0, 0);
        f32x4 ag0 = MFMA16(a0, Bf0[2][0], bias0[2], 0, 0, 0);
        f32x4 ao0 = MFMA16(a0, Bf0[3][0], bias0[3], 0, 0, 0);
        ai0 = MFMA16(a1, Bf0[0][1], ai0, 0, 0, 0);
        af0 = MFMA16(a1, Bf0[1][1], af0, 0, 0, 0);
        ag0 = MFMA16(a1, Bf0[2][1], ag0, 0, 0, 0);
        ao0 = MFMA16(a1, Bf0[3][1], ao0, 0, 0, 0);
        ai0 = MFMA16(a2, Bf0[0][2], ai0, 0, 0, 0);
        af0 = MFMA16(a2, Bf0[1][2], af0, 0, 0, 0);
        ag0 = MFMA16(a2, Bf0[2][2], ag0, 0, 0, 0);
        ao0 = MFMA16(a2, Bf0[3][2], ao0, 0, 0, 0);

        // INTERLEAVE: {4 L1 MFMAs on frag k ; gates0 row k} x4.
        // gates0 rows depend only on completed L0 accumulators; L1 MFMAs
        // depend only on a0/a1/b2/b3 -> matrix pipe runs under trans pipe.
        float h00, h01, h02, h03;
        f32x4 ai1 = MFMA16(a0, Bf1[0][0], bias1[0], 0, 0, 0);
        f32x4 af1 = MFMA16(a0, Bf1[1][0], bias1[1], 0, 0, 0);
        f32x4 ag1 = MFMA16(a0, Bf1[2][0], bias1[2], 0, 0, 0);
        f32x4 ao1 = MFMA16(a0, Bf1[3][0], bias1[3], 0, 0, 0);
        h00 = gate_row(ai0[0], af0[0], ag0[0], ao0[0], cc0[0]);
        ai1 = MFMA16(a1, Bf1[0][1], ai1, 0, 0, 0);
        af1 = MFMA16(a1, Bf1[1][1], af1, 0, 0, 0);
        ag1 = MFMA16(a1, Bf1[2][1], ag1, 0, 0, 0);
        ao1 = MFMA16(a1, Bf1[3][1], ao1, 0, 0, 0);
        h01 = gate_row(ai0[1], af0[1], ag0[1], ao0[1], cc0[1]);
        ai1 = MFMA16(b2, Bf1[0][2], ai1, 0, 0, 0);
        af1 = MFMA16(b2, Bf1[1][2], af1, 0, 0, 0);
        ag1 = MFMA16(b2, Bf1[2][2], ag1, 0, 0, 0);
        ao1 = MFMA16(b2, Bf1[3][2], ao1, 0, 0, 0);
        h02 = gate_row(ai0[2], af0[2], ag0[2], ao0[2], cc0[2]);
        ai1 = MFMA16(b3, Bf1[0][3], ai1, 0, 0, 0);
        af1 = MFMA16(b3, Bf1[1][3], af1, 0, 0, 0);
        ag1 = MFMA16(b3, Bf1[2][3], ag1, 0, 0, 0);
        ao1 = MFMA16(b3, Bf1[3][3], ao1, 0, 0, 0);
        h03 = gate_row(ai0[3], af0[3], ag0[3], ao0[3], cc0[3]);

        const unsigned p00 = pkbf(h00, h01), p01 = pkbf(h02, h03);
        lds16[wr0]      = (unsigned short)p00;
        lds16[wr0 + 8]  = (unsigned short)(p00 >> 16);
        lds16[wr0 + 16] = (unsigned short)p01;
        lds16[wr0 + 24] = (unsigned short)(p01 >> 16);

        unsigned hp1[2];
        gates4(ai1, af1, ag1, ao1, cc1, hp1);
        lds16[wrH1]      = (unsigned short)hp1[0];
        lds16[wrH1 + 8]  = (unsigned short)(hp1[0] >> 16);
        lds16[wrH1 + 16] = (unsigned short)hp1[1];
        lds16[wrH1 + 24] = (unsigned short)(hp1[1] >> 16);

        BAR();
        rdA ^= A0TOG; wr0 ^= A0TOG; rdH1 ^= A1TOG; wrH1 ^= A1TOG;
    }

    // ---- Peeled it=TB: L1 only (step t1 = TB-1) ----
    {
        const short8 a0 = *(const short8*)(lds16 + rdA);
        const short8 a1 = *(const short8*)(lds16 + rdA + 512);
        const short8 b2 = *(const short8*)(lds16 + rdH1);
        const short8 b3 = *(const short8*)(lds16 + rdH1 + 512);
        f32x4 ai = MFMA16(a0, Bf1[0][0], bias1[0], 0, 0, 0);
        f32x4 af = MFMA16(a0, Bf1[1][0], bias1[1], 0, 0, 0);
        f32x4 ag = MFMA16(a0, Bf1[2][0], bias1[2], 0, 0, 0);
        f32x4 ao = MFMA16(a0, Bf1[3][0], bias1[3], 0, 0, 0);
        ai = MFMA16(a1, Bf1[0][1], ai, 0, 0, 0);
        af = MFMA16(a1, Bf1[1][1], af, 0, 0, 0);
        ag = MFMA16(a1, Bf1[2][1], ag, 0, 0, 0);
        ao = MFMA16(a1, Bf1[3][1], ao, 0, 0, 0);
        ai = MFMA16(b2, Bf1[0][2], ai, 0, 0, 0);
        af = MFMA16(b2, Bf1[1][2], af, 0, 0, 0);
        ag = MFMA16(b2, Bf1[2][2], ag, 0, 0, 0);
        ao = MFMA16(b2, Bf1[3][2], ao, 0, 0, 0);
        ai = MFMA16(b3, Bf1[0][3], ai, 0, 0, 0);
        af = MFMA16(b3, Bf1[1][3], af, 0, 0, 0);
        ag = MFMA16(b3, Bf1[2][3], ag, 0, 0, 0);
        ao = MFMA16(b3, Bf1[3][3], ao, 0, 0, 0);
        unsigned hp[2];
        gates4(ai, af, ag, ao, cc1, hp);
        lds16[wrH1]      = (unsigned short)hp[0];
        lds16[wrH1 + 8]  = (unsigned short)(hp[0] >> 16);
        lds16[wrH1 + 16] = (unsigned short)hp[1];
        lds16[wrH1 + 24] = (unsigned short)(hp[1] >> 16);
        BAR();
    }

    // Final FC: h1(511) written at it=512 -> A1 parity 1
    if (tid < BSL) {
        float s = bfc[0];
        #pragma unroll 8
        for (int j = 0; j < 64; ++j)
            s += bf2f(lds16[A1BASE + A1TOG + (j >> 3) * 128 + tid * 8 + (j & 7)]) * Wfc[j];
        out[rb + tid] = s;
    }
}

extern "C" void kernel_launch(void* const* d_in, const int* in_sizes, int n_in,
                              void* d_out, int out_size, void* d_ws, size_t ws_size,
                              hipStream_t stream) {
    const float* x    = (const float*)d_in[0];
    const float* Wih0 = (const float*)d_in[1];
    const float* Whh0 = (const float*)d_in[2];
    const float* bih0 = (const float*)d_in[3];
    const float* bhh0 = (const float*)d_in[4];
    const float* Wih1 = (const float*)d_in[5];
    const float* Whh1 = (const float*)d_in[6];
    const float* bih1 = (const float*)d_in[7];
    const float* bhh1 = (const float*)d_in[8];
    const float* Wfc  = (const float*)d_in[9];
    const float* bfc  = (const float*)d_in[10];
    float* out = (float*)d_out;

    dim3 grid(BTOT / BSL);   // 256 blocks = 1 per CU
    dim3 block(256);         // 4 waves: each owns 16 hidden cols, BOTH layers
    lstm2_fused<<<grid, block, 0, stream>>>(x, Wih0, Whh0, bih0, bhh0,
                                            Wih1, Whh1, bih1, bhh1, Wfc, bfc, out);
}

// Round 3
// 560.685 us; speedup vs baseline: 1.0051x; 1.0051x over previous
//
#include <hip/hip_runtime.h>

// Problem constants (fixed by the reference)
#define BTOT 4096
#define TB   512
#define BD   8
#define BSL  16    // MFMA tile M (R6 lesson: BSL=8 duplicates work chip-wide)

// LDS element map (uint16 elements, 2 B), k-major block layout:
//   A-tile element (row,k) at blk*128 + row*8 + (k&7), blk = k>>3
//   -> lane (q,ln)'s A-frag (row=ln, k=ki*32+q*8+j) = 16 contiguous bytes
//      at (ki*4+q)*128 + ln*8  => ds_read_b128, conflict-free per 8-lane group.
// A0 (h0, K=64): parity p at p*1024                      (els 0..2047)
// A1 (h1, K=64): parity p at 2048 + p*1024               (els 2048..4095)
// ZERO block (always 0, x-frag source for q>0 lanes):    (els 4096..4223)
// XB x chunks (64 t x 16 rows x 8 d, double-buffered):   (els 8192..24575)
#define A0TOG  1024
#define A1BASE 2048
#define A1TOG  1024
#define ZBASE  4096
#define XBASE  8192
#define NLDS   24576   // 48 KiB

typedef __attribute__((ext_vector_type(8))) short  short8;  // MFMA A/B frag
typedef __attribute__((ext_vector_type(4))) float  f32x4;   // MFMA C/D frag

#define MFMA16 __builtin_amdgcn_mfma_f32_16x16x32_bf16

// Raw barrier: wait only LDS ops (ds_write visibility), leave vmcnt
// outstanding so the ph48 global x-prefetch hides across ~14 barriers.
#define BAR() asm volatile("s_waitcnt lgkmcnt(0)\n\ts_barrier" ::: "memory")

static __device__ __forceinline__ unsigned short f2bf(float f) {
    unsigned u = __float_as_uint(f);
    u += 0x7fffu + ((u >> 16) & 1u);
    return (unsigned short)(u >> 16);
}
static __device__ __forceinline__ float bf2f(unsigned short h) {
    return __uint_as_float(((unsigned)h) << 16);
}
static __device__ __forceinline__ unsigned pkbf(float a, float b) {
    unsigned r;  // gfx950 HW packed f32->bf16 (RNE); dest must be VGPR
    asm("v_cvt_pk_bf16_f32 %0, %1, %2" : "=v"(r) : "v"(a), "v"(b));
    return r;
}

// Fast reciprocal OFF the trans pipe: bit-hack seed (~3.4% err) + 2 Newton
// iters -> ~1e-6 rel err (far below bf16 quantization). 5 VALU ops instead
// of a 16-cy trans-pipe v_rcp. Accuracy harness-verified in R2 (absmax
// unchanged at 4.88e-4). Valid for d in (1, 2^30): always true here.
static __device__ __forceinline__ float fastrcp(float d) {
    float y = __uint_as_float(0x7EF311C3u - __float_as_uint(d));
    y = y * (2.0f - d * y);
    y = y * (2.0f - d * y);
    return y;
}

// Joint-denominator gate math: 5 exp2 (trans) + 2 fastrcp (VALU) per unit.
// Pre-folded scales: i,f,o rows x -log2(e); g row x 2*log2(e).
//   c' = f*c + i*g = [c*Ai*Ag + Af*(eg-1)] / (Af*Ai*Ag)
//   h  = o*tanh(c') = (ec-1) / (Ao*(ec+1)),  ec = 2^(2*log2(e)*c')
static __device__ __forceinline__ void gates4(
    const f32x4 ai, const f32x4 af, const f32x4 ag, const f32x4 ao,
    float cc[4], unsigned hp[2])
{
    float h[4];
    #pragma unroll
    for (int r = 0; r < 4; ++r) {
        const float ei = __builtin_amdgcn_exp2f(ai[r]);
        const float ef = __builtin_amdgcn_exp2f(af[r]);
        const float eg = __builtin_amdgcn_exp2f(ag[r]);
        const float eo = __builtin_amdgcn_exp2f(ao[r]);
        const float Ai = 1.f + ei, Af = 1.f + ef, Ag = 1.f + eg, Ao = 1.f + eo;
        const float P    = Ai * Ag;
        const float numer = cc[r] * P + Af * (eg - 1.f);
        const float rD   = fastrcp(Af * P);
        cc[r] = numer * rD;
        const float ec = __builtin_amdgcn_exp2f(2.88539008f * cc[r]);
        const float rH = fastrcp(Ao * (ec + 1.f));
        h[r] = (ec - 1.f) * rH;
    }
    hp[0] = pkbf(h[0], h[1]); hp[1] = pkbf(h[2], h[3]);
}

// MERGED-WAVE DESIGN (R1 structure, verbatim — 465 us known-good): 4 waves,
// each owns 16 hidden cols for BOTH layers. R2 lesson: do NOT hand-interleave
// MFMA/gate code at source level; let the compiler schedule. This round's
// single change: rcp -> fastrcp inside gates4 (trans-pipe cut only).
__global__ __launch_bounds__(256, 1) void lstm2_fused(
    const float* __restrict__ x,
    const float* __restrict__ Wih0, const float* __restrict__ Whh0,
    const float* __restrict__ bih0, const float* __restrict__ bhh0,
    const float* __restrict__ Wih1, const float* __restrict__ Whh1,
    const float* __restrict__ bih1, const float* __restrict__ bhh1,
    const float* __restrict__ Wfc,  const float* __restrict__ bfc,
    float* __restrict__ out)
{
    __shared__ __align__(16) unsigned short lds16[NLDS];

    const int tid  = threadIdx.x;
    const int wid  = tid >> 6;           // 4 waves; wave g = cols 16g..16g+15
    const int lane = tid & 63;
    const int q    = lane >> 4;
    const int ln   = lane & 15;
    const int rb   = blockIdx.x * BSL;
    const int jc   = wid * 16 + ln;      // hidden col this lane owns (both layers)

    const float SCI = -1.44269504f;
    const float SCG =  2.88539008f;

    // ---- Weight fragments -> registers (both layers), bf16, scales folded ----
    short8 Bf0[4][3];                    // L0: k 0..63 = Whh0, 64..71 = Wih0
    short8 Bf1[4][4];                    // L1: k 0..63 = Wih1, 64..127 = Whh1
    #pragma unroll
    for (int G = 0; G < 4; ++G) {
        const int n = G * 64 + jc;
        const float sc = (G == 2) ? SCG : SCI;
        #pragma unroll
        for (int ki = 0; ki < 3; ++ki) {
            union { unsigned short u[8]; short8 v; } t;
            #pragma unroll
            for (int j = 0; j < 8; ++j) {
                const int k = ki * 32 + q * 8 + j;
                float wv = 0.0f;
                if (k < 64)      wv = Whh0[n * 64 + k];
                else if (k < 72) wv = Wih0[n * 8 + (k - 64)];
                t.u[j] = f2bf(sc * wv);
            }
            Bf0[G][ki] = t.v;
        }
        #pragma unroll
        for (int ki = 0; ki < 4; ++ki) {
            union { unsigned short u[8]; short8 v; } t;
            #pragma unroll
            for (int j = 0; j < 8; ++j) {
                const int k = ki * 32 + q * 8 + j;
                const float wv = (k < 64) ? Wih1[n * 64 + k]
                                          : Whh1[n * 64 + (k - 64)];
                t.u[j] = f2bf(sc * wv);
            }
            Bf1[G][ki] = t.v;
        }
    }
    f32x4 bias0[4], bias1[4];            // bias as persistent MFMA C-operand
    #pragma unroll
    for (int G = 0; G < 4; ++G) {
        const int n = G * 64 + jc;
        const float sc = (G == 2) ? SCG : SCI;
        const float b0 = sc * (bih0[n] + bhh0[n]);
        const float b1 = sc * (bih1[n] + bhh1[n]);
        bias0[G] = (f32x4){b0, b0, b0, b0};
        bias1[G] = (f32x4){b1, b1, b1, b1};
    }

    // ---- Prologue: zero A0/A1/ZERO, stage x chunk 0 ----
    {
        unsigned* z = (unsigned*)lds16;   // els 0..4223 = 2112 dwords
        #pragma unroll
        for (int i = 0; i < 9; ++i) {
            const int id = tid + i * 256;
            if (id < 2112) z[id] = 0;
        }
    }
    const int srow = tid >> 4, su = tid & 15;  // stager: 32 floats/thread
    {
        const float* gp = x + (size_t)(rb + srow) * (TB * BD) + su * 32;
        float4 v[8];
        #pragma unroll
        for (int i = 0; i < 8; ++i) v[i] = ((const float4*)gp)[i];
        #pragma unroll
        for (int tt = 0; tt < 4; ++tt) {
            uint4 s;
            s.x = pkbf(v[2*tt].x,   v[2*tt].y);   s.y = pkbf(v[2*tt].z,   v[2*tt].w);
            s.z = pkbf(v[2*tt+1].x, v[2*tt+1].y); s.w = pkbf(v[2*tt+1].z, v[2*tt+1].w);
            const int el = XBASE + (su * 4 + tt) * 128 + srow * 8;
            *(uint4*)(lds16 + el) = s;
        }
    }
    __syncthreads();

    // ---- Hoisted ping-pong pointers (element indices), XOR-toggled ----
    const int rbase = q * 128 + ln * 8;                    // A-frag read base
    const int wb    = (jc >> 3) * 128 + q * 32 + (jc & 7); // h-write base
    const int ln8   = ln * 8;
    const int zaddr = ZBASE + ln8;       // q>0 x-frag source (always zero)
    int rdA  = rbase;                    // h0(t-1): read by BOTH layers
    int wr0  = A0TOG + wb;               // h0(t) -> other parity
    int rdH1 = A1BASE + rbase;           // h1(t1-1)
    int wrH1 = A1BASE + A1TOG + wb;      // h1(t1) -> other parity

    float cc0[4] = {0.f, 0.f, 0.f, 0.f};
    float cc1[4] = {0.f, 0.f, 0.f, 0.f};
    float4 px[8];                        // x-chunk global prefetch registers

    // ---- Peeled it=0: L0 only (h0(-1)=h1(-1)=0) ----
    {
        const short8 a0 = *(const short8*)(lds16 + rdA);
        const short8 a1 = *(const short8*)(lds16 + rdA + 512);
        const int xaddr = (q == 0) ? (XBASE + 0 + ln8) : zaddr;
        const short8 a2 = *(const short8*)(lds16 + xaddr);
        f32x4 ai = MFMA16(a0, Bf0[0][0], bias0[0], 0, 0, 0);
        f32x4 af = MFMA16(a0, Bf0[1][0], bias0[1], 0, 0, 0);
        f32x4 ag = MFMA16(a0, Bf0[2][0], bias0[2], 0, 0, 0);
        f32x4 ao = MFMA16(a0, Bf0[3][0], bias0[3], 0, 0, 0);
        ai = MFMA16(a1, Bf0[0][1], ai, 0, 0, 0);
        af = MFMA16(a1, Bf0[1][1], af, 0, 0, 0);
        ag = MFMA16(a1, Bf0[2][1], ag, 0, 0, 0);
        ao = MFMA16(a1, Bf0[3][1], ao, 0, 0, 0);
        ai = MFMA16(a2, Bf0[0][2], ai, 0, 0, 0);
        af = MFMA16(a2, Bf0[1][2], af, 0, 0, 0);
        ag = MFMA16(a2, Bf0[2][2], ag, 0, 0, 0);
        ao = MFMA16(a2, Bf0[3][2], ao, 0, 0, 0);
        unsigned hp[2];
        gates4(ai, af, ag, ao, cc0, hp);
        lds16[wr0]      = (unsigned short)hp[0];
        lds16[wr0 + 8]  = (unsigned short)(hp[0] >> 16);
        lds16[wr0 + 16] = (unsigned short)hp[1];
        lds16[wr0 + 24] = (unsigned short)(hp[1] >> 16);
        BAR();
        rdA ^= A0TOG; wr0 ^= A0TOG; rdH1 ^= A1TOG; wrH1 ^= A1TOG;
    }

    // ---- Steady state it=1..TB-1: one straight-line block, both layers ----
    for (int it = 1; it < TB; ++it) {
        const int ph = it & 63;
        if (ph == 48 && it + 16 < TB) {  // prefetch next chunk -> regs
            const int t0 = (it & ~63) + 64;
            const float* gp = x + (size_t)(rb + srow) * (TB * BD) + t0 * BD + su * 32;
            #pragma unroll
            for (int i = 0; i < 8; ++i) px[i] = ((const float4*)gp)[i];
        }
        if (ph == 62 && it + 2 < TB) {   // pack + write to OTHER XB buffer
            const int t0 = (it & ~63) + 64;
            #pragma unroll
            for (int tt = 0; tt < 4; ++tt) {
                uint4 s;
                s.x = pkbf(px[2*tt].x,   px[2*tt].y);   s.y = pkbf(px[2*tt].z,   px[2*tt].w);
                s.z = pkbf(px[2*tt+1].x, px[2*tt+1].y); s.w = pkbf(px[2*tt+1].z, px[2*tt+1].w);
                const int el = XBASE + ((t0 + su * 4 + tt) & 127) * 128 + srow * 8;
                *(uint4*)(lds16 + el) = s;
            }
        }

        // Shared reads: h0(it-1) feeds L0 recurrence AND L1 input.
        const short8 a0 = *(const short8*)(lds16 + rdA);
        const short8 a1 = *(const short8*)(lds16 + rdA + 512);
        const short8 b2 = *(const short8*)(lds16 + rdH1);        // h1 k 0..31
        const short8 b3 = *(const short8*)(lds16 + rdH1 + 512);  // h1 k 32..63
        const int xaddr = (q == 0) ? (XBASE + ((it & 127) << 7) + ln8) : zaddr;
        const short8 a2 = *(const short8*)(lds16 + xaddr);

        // L0 MFMAs (step t = it)
        f32x4 ai0 = MFMA16(a0, Bf0[0][0], bias0[0], 0, 0, 0);
        f32x4 af0 = MFMA16(a0, Bf0[1][0], bias0[1], 0, 0, 0);
        f32x4 ag0 = MFMA16(a0, Bf0[2][0], bias0[2], 0, 0, 0);
        f32x4 ao0 = MFMA16(a0, Bf0[3][0], bias0[3], 0, 0, 0);
        ai0 = MFMA16(a1, Bf0[0][1], ai0, 0, 0, 0);
        af0 = MFMA16(a1, Bf0[1][1], af0, 0, 0, 0);
        ag0 = MFMA16(a1, Bf0[2][1], ag0, 0, 0, 0);
        ao0 = MFMA16(a1, Bf0[3][1], ao0, 0, 0, 0);
        ai0 = MFMA16(a2, Bf0[0][2], ai0, 0, 0, 0);
        af0 = MFMA16(a2, Bf0[1][2], af0, 0, 0, 0);
        ag0 = MFMA16(a2, Bf0[2][2], ag0, 0, 0, 0);
        ao0 = MFMA16(a2, Bf0[3][2], ao0, 0, 0, 0);

        // L1 MFMAs (step t1 = it-1) — independent of L0's gate chain
        f32x4 ai1 = MFMA16(a0, Bf1[0][0], bias1[0], 0, 0, 0);
        f32x4 af1 = MFMA16(a0, Bf1[1][0], bias1[1], 0, 0, 0);
        f32x4 ag1 = MFMA16(a0, Bf1[2][0], bias1[2], 0, 0, 0);
        f32x4 ao1 = MFMA16(a0, Bf1[3][0], bias1[3], 0, 0, 0);
        ai1 = MFMA16(a1, Bf1[0][1], ai1, 0, 0, 0);
        af1 = MFMA16(a1, Bf1[1][1], af1, 0, 0, 0);
        ag1 = MFMA16(a1, Bf1[2][1], ag1, 0, 0, 0);
        ao1 = MFMA16(a1, Bf1[3][1], ao1, 0, 0, 0);
        ai1 = MFMA16(b2, Bf1[0][2], ai1, 0, 0, 0);
        af1 = MFMA16(b2, Bf1[1][2], af1, 0, 0, 0);
        ag1 = MFMA16(b2, Bf1[2][2], ag1, 0, 0, 0);
        ao1 = MFMA16(b2, Bf1[3][2], ao1, 0, 0, 0);
        ai1 = MFMA16(b3, Bf1[0][3], ai1, 0, 0, 0);
        af1 = MFMA16(b3, Bf1[1][3], af1, 0, 0, 0);
        ag1 = MFMA16(b3, Bf1[2][3], ag1, 0, 0, 0);
        ao1 = MFMA16(b3, Bf1[3][3], ao1, 0, 0, 0);

        unsigned hp0[2], hp1[2];
        gates4(ai0, af0, ag0, ao0, cc0, hp0);
        lds16[wr0]      = (unsigned short)hp0[0];
        lds16[wr0 + 8]  = (unsigned short)(hp0[0] >> 16);
        lds16[wr0 + 16] = (unsigned short)hp0[1];
        lds16[wr0 + 24] = (unsigned short)(hp0[1] >> 16);

        gates4(ai1, af1, ag1, ao1, cc1, hp1);
        lds16[wrH1]      = (unsigned short)hp1[0];
        lds16[wrH1 + 8]  = (unsigned short)(hp1[0] >> 16);
        lds16[wrH1 + 16] = (unsigned short)hp1[1];
        lds16[wrH1 + 24] = (unsigned short)(hp1[1] >> 16);

        BAR();
        rdA ^= A0TOG; wr0 ^= A0TOG; rdH1 ^= A1TOG; wrH1 ^= A1TOG;
    }

    // ---- Peeled it=TB: L1 only (step t1 = TB-1) ----
    {
        const short8 a0 = *(const short8*)(lds16 + rdA);
        const short8 a1 = *(const short8*)(lds16 + rdA + 512);
        const short8 b2 = *(const short8*)(lds16 + rdH1);
        const short8 b3 = *(const short8*)(lds16 + rdH1 + 512);
        f32x4 ai = MFMA16(a0, Bf1[0][0], bias1[0], 0, 0, 0);
        f32x4 af = MFMA16(a0, Bf1[1][0], bias1[1], 0, 0, 0);
        f32x4 ag = MFMA16(a0, Bf1[2][0], bias1[2], 0, 0, 0);
        f32x4 ao = MFMA16(a0, Bf1[3][0], bias1[3], 0, 0, 0);
        ai = MFMA16(a1, Bf1[0][1], ai, 0, 0, 0);
        af = MFMA16(a1, Bf1[1][1], af, 0, 0, 0);
        ag = MFMA16(a1, Bf1[2][1], ag, 0, 0, 0);
        ao = MFMA16(a1, Bf1[3][1], ao, 0, 0, 0);
        ai = MFMA16(b2, Bf1[0][2], ai, 0, 0, 0);
        af = MFMA16(b2, Bf1[1][2], af, 0, 0, 0);
        ag = MFMA16(b2, Bf1[2][2], ag, 0, 0, 0);
        ao = MFMA16(b2, Bf1[3][2], ao, 0, 0, 0);
        ai = MFMA16(b3, Bf1[0][3], ai, 0, 0, 0);
        af = MFMA16(b3, Bf1[1][3], af, 0, 0, 0);
        ag = MFMA16(b3, Bf1[2][3], ag, 0, 0, 0);
        ao = MFMA16(b3, Bf1[3][3], ao, 0, 0, 0);
        unsigned hp[2];
        gates4(ai, af, ag, ao, cc1, hp);
        lds16[wrH1]      = (unsigned short)hp[0];
        lds16[wrH1 + 8]  = (unsigned short)(hp[0] >> 16);
        lds16[wrH1 + 16] = (unsigned short)hp[1];
        lds16[wrH1 + 24] = (unsigned short)(hp[1] >> 16);
        BAR();
    }

    // Final FC: h1(511) written at it=512 -> A1 parity 1
    if (tid < BSL) {
        float s = bfc[0];
        #pragma unroll 8
        for (int j = 0; j < 64; ++j)
            s += bf2f(lds16[A1BASE + A1TOG + (j >> 3) * 128 + tid * 8 + (j & 7)]) * Wfc[j];
        out[rb + tid] = s;
    }
}

extern "C" void kernel_launch(void* const* d_in, const int* in_sizes, int n_in,
                              void* d_out, int out_size, void* d_ws, size_t ws_size,
                              hipStream_t stream) {
    const float* x    = (const float*)d_in[0];
    const float* Wih0 = (const float*)d_in[1];
    const float* Whh0 = (const float*)d_in[2];
    const float* bih0 = (const float*)d_in[3];
    const float* bhh0 = (const float*)d_in[4];
    const float* Wih1 = (const float*)d_in[5];
    const float* Whh1 = (const float*)d_in[6];
    const float* bih1 = (const float*)d_in[7];
    const float* bhh1 = (const float*)d_in[8];
    const float* Wfc  = (const float*)d_in[9];
    const float* bfc  = (const float*)d_in[10];
    float* out = (float*)d_out;

    dim3 grid(BTOT / BSL);   // 256 blocks = 1 per CU
    dim3 block(256);         // 4 waves: each owns 16 hidden cols, BOTH layers
    lstm2_fused<<<grid, block, 0, stream>>>(x, Wih0, Whh0, bih0, bhh0,
                                            Wih1, Whh1, bih1, bhh1, Wfc, bfc, out);
}

// Round 4
// 545.338 us; speedup vs baseline: 1.0334x; 1.0281x over previous
//
#include <hip/hip_runtime.h>

// Problem constants (fixed by the reference)
#define BTOT 4096
#define TB   512
#define BD   8
#define BSL  16    // MFMA tile M

// LDS element map (uint16 elements, 2 B), k-major block layout:
//   A-tile element (row,k) at blk*128 + row*8 + (k&7), blk = k>>3
//   -> lane (q,ln)'s A-frag (row=ln, k=ki*32+q*8+j) = 16 contiguous bytes
//      at (ki*4+q)*128 + ln*8  => ds_read_b128, conflict-free per 8-lane group.
// A0 (h0, K=64): parity p at p*1024                      (els 0..2047)
// A1 (h1, K=64): parity p at 2048 + p*1024               (els 2048..4095)
// ZERO block (always 0, x-frag source for q>0 lanes):    (els 4096..4223)
// XB x chunks (64 t x 16 rows x 8 d, double-buffered):   (els 8192..24575)
#define A0TOG  1024
#define A1BASE 2048
#define A1TOG  1024
#define ZBASE  4096
#define XBASE  8192
#define NLDS   24576   // 48 KiB

typedef __attribute__((ext_vector_type(8))) short  short8;  // MFMA A/B frag
typedef __attribute__((ext_vector_type(4))) float  f32x4;   // MFMA C/D frag

#define MFMA16 __builtin_amdgcn_mfma_f32_16x16x32_bf16

// Raw barrier: wait only LDS ops (ds_write visibility), leave vmcnt
// outstanding so the ph48 global x-prefetch hides across barriers.
#define BAR() asm volatile("s_waitcnt lgkmcnt(0)\n\ts_barrier" ::: "memory")

static __device__ __forceinline__ unsigned short f2bf(float f) {
    unsigned u = __float_as_uint(f);
    u += 0x7fffu + ((u >> 16) & 1u);
    return (unsigned short)(u >> 16);
}
static __device__ __forceinline__ float bf2f(unsigned short h) {
    return __uint_as_float(((unsigned)h) << 16);
}
static __device__ __forceinline__ unsigned pkbf(float a, float b) {
    unsigned r;  // gfx950 HW packed f32->bf16 (RNE); dest must be VGPR
    asm("v_cvt_pk_bf16_f32 %0, %1, %2" : "=v"(r) : "v"(a), "v"(b));
    return r;
}

// Joint-denominator gate math: 7 trans/unit (5 exp2 + 2 rcp).
// R3 lesson: plain v_rcp BEATS Newton fastrcp in this latency-bound regime
// (one issue slot; latency hidden by the 3 other independent rows).
// Pre-folded scales: i,f,o rows x -log2(e); g row x 2*log2(e).
//   c' = f*c + i*g = [c*Ai*Ag + Af*(eg-1)] / (Af*Ai*Ag)
//   h  = o*tanh(c') = (ec-1) / (Ao*(ec+1)),  ec = 2^(2*log2(e)*c')
static __device__ __forceinline__ void gates4(
    const f32x4 ai, const f32x4 af, const f32x4 ag, const f32x4 ao,
    float cc[4], unsigned hp[2])
{
    float h[4];
    #pragma unroll
    for (int r = 0; r < 4; ++r) {
        const float ei = __builtin_amdgcn_exp2f(ai[r]);
        const float ef = __builtin_amdgcn_exp2f(af[r]);
        const float eg = __builtin_amdgcn_exp2f(ag[r]);
        const float eo = __builtin_amdgcn_exp2f(ao[r]);
        const float Ai = 1.f + ei, Af = 1.f + ef, Ag = 1.f + eg, Ao = 1.f + eo;
        const float P    = Ai * Ag;
        const float numer = cc[r] * P + Af * (eg - 1.f);
        const float rD   = __builtin_amdgcn_rcpf(Af * P);
        cc[r] = numer * rD;
        const float ec = __builtin_amdgcn_exp2f(2.88539008f * cc[r]);
        const float rH = __builtin_amdgcn_rcpf(Ao * (ec + 1.f));
        h[r] = (ec - 1.f) * rH;
    }
    hp[0] = pkbf(h[0], h[1]); hp[1] = pkbf(h[2], h[3]);
}

// STAGGERED TWO-SLOT DESIGN (this round): 8 waves (4 L0 + 4 L1, 2/SIMD),
// each step = two barrier slots with OFFSET roles:
//   slot A: L0 does MFMA(t)   while L1 does gates(t-2)+write
//   slot B: L0 does gates(t)  while L1 does MFMA(t-1)
// So each SIMD always has one wave on the MFMA pipe and one on VALU/trans.
// R0/R1 proved phase-locked waves serialize (543 MFMA + ~1240 gate cy);
// m114 proved role-split waves co-execute. This forces the split.
__global__ __launch_bounds__(512, 2) void lstm2_fused(
    const float* __restrict__ x,
    const float* __restrict__ Wih0, const float* __restrict__ Whh0,
    const float* __restrict__ bih0, const float* __restrict__ bhh0,
    const float* __restrict__ Wih1, const float* __restrict__ Whh1,
    const float* __restrict__ bih1, const float* __restrict__ bhh1,
    const float* __restrict__ Wfc,  const float* __restrict__ bfc,
    float* __restrict__ out)
{
    __shared__ __align__(16) unsigned short lds16[NLDS];

    const int tid  = threadIdx.x;
    const int wid  = tid >> 6;           // 8 waves: 0..3 = layer 0, 4..7 = layer 1
    const int lane = tid & 63;
    const int q    = lane >> 4;
    const int ln   = lane & 15;
    const int rb   = blockIdx.x * BSL;

    const bool L1w = (wid >= 4);
    const int  g   = L1w ? (wid - 4) : wid;
    const int  jc  = g * 16 + ln;        // hidden col this lane owns for all 4 gates

    const float SCI = -1.44269504f;
    const float SCG =  2.88539008f;

    // ---- Weight fragments -> registers, bf16, exp2-scale pre-folded ----
    short8 Bf[4][4];                     // [gate][k_iter]; L0 uses ki 0..2
    #pragma unroll
    for (int G = 0; G < 4; ++G) {
        const int n = G * 64 + jc;
        const float sc = (G == 2) ? SCG : SCI;
        #pragma unroll
        for (int ki = 0; ki < 4; ++ki) {
            union { unsigned short u[8]; short8 v; } t;
            #pragma unroll
            for (int j = 0; j < 8; ++j) {
                const int k = ki * 32 + q * 8 + j;
                float wv = 0.0f;
                if (!L1w) {
                    if (ki < 3) {
                        if (k < 64)      wv = Whh0[n * 64 + k];          // recurrent
                        else if (k < 72) wv = Wih0[n * 8 + (k - 64)];    // x proj
                    }
                } else {
                    if (k < 64)          wv = Wih1[n * 64 + k];          // from h0
                    else                 wv = Whh1[n * 64 + (k - 64)];   // recurrent
                }
                t.u[j] = f2bf(sc * wv);
            }
            Bf[G][ki] = t.v;
        }
    }
    // Bias as persistent MFMA C-operand
    f32x4 biasv[4];
    #pragma unroll
    for (int G = 0; G < 4; ++G) {
        const int n = G * 64 + jc;
        const float sc = (G == 2) ? SCG : SCI;
        const float b = sc * (L1w ? (bih1[n] + bhh1[n]) : (bih0[n] + bhh0[n]));
        biasv[G] = (f32x4){b, b, b, b};
    }

    // ---- Prologue: zero A0/A1/ZERO (h_{-1}=0), stage x chunk 0 ----
    {
        unsigned* z = (unsigned*)lds16;   // els 0..4223 = 2112 dwords
        #pragma unroll
        for (int i = 0; i < 5; ++i) {
            const int id = tid + i * 512;
            if (id < 2112) z[id] = 0;
        }
    }
    const int srow = tid >> 5, su = tid & 31;   // stager mapping: 16 floats/thread
    {
        const float* gp = x + (size_t)(rb + srow) * (TB * BD) + su * 16;
        const float4 v0 = ((const float4*)gp)[0];
        const float4 v1 = ((const float4*)gp)[1];
        const float4 v2 = ((const float4*)gp)[2];
        const float4 v3 = ((const float4*)gp)[3];
        uint4 s0, s1;
        s0.x = pkbf(v0.x, v0.y); s0.y = pkbf(v0.z, v0.w);
        s0.z = pkbf(v1.x, v1.y); s0.w = pkbf(v1.z, v1.w);
        s1.x = pkbf(v2.x, v2.y); s1.y = pkbf(v2.z, v2.w);
        s1.z = pkbf(v3.x, v3.y); s1.w = pkbf(v3.z, v3.w);
        const int el = XBASE + (su * 2) * 128 + srow * 8;
        *(uint4*)(lds16 + el)       = s0;
        *(uint4*)(lds16 + el + 128) = s1;
    }
    __syncthreads();

    // ---- Ping-pong pointers (element indices), toggled once per step ----
    // parity invariants at iteration t:
    //   rdA  = h0(t-1) frags, parity t&1        (read by L0 slot A, L1 slot B)
    //   wr0  = h0(t)  write,  parity (t+1)&1    (L0 slot B)
    //   rdH1 = h1(t-2) frags, parity t&1        (L1 slot B)
    //   wrH1 = h1(t-2) write, parity t&1        (L1 slot A; read after 1 BAR)
    const int rbase = q * 128 + ln * 8;                    // A-frag read base
    const int wb    = (jc >> 3) * 128 + q * 32 + (jc & 7); // h-write base
    const int ln8   = ln * 8;
    const int zaddr = ZBASE + ln8;       // q>0 x-frag source (always zero)
    int rdA  = rbase;
    int wr0  = A0TOG + wb;
    int rdH1 = A1BASE + rbase;
    int wrH1 = A1BASE + wb;

    float cc[4] = {0.f, 0.f, 0.f, 0.f};  // cell state (role-dependent layer)
    float4 px0, px1, px2, px3;           // x-chunk global prefetch registers
    f32x4 ai0, af0, ag0, ao0;            // L0 acc: slot A -> slot B (same iter)
    f32x4 ai1, af1, ag1, ao1;            // L1 acc: slot B -> next iter slot A

    for (int t = 0; t < TB + 2; ++t) {
        const int ph = t & 63;
        if (ph == 48 && t + 16 < TB) {   // prefetch next chunk -> regs
            const int t0 = (t & ~63) + 64;
            const float* gp = x + (size_t)(rb + srow) * (TB * BD) + t0 * BD + su * 16;
            px0 = ((const float4*)gp)[0];
            px1 = ((const float4*)gp)[1];
            px2 = ((const float4*)gp)[2];
            px3 = ((const float4*)gp)[3];
        }

        // ---------------- SLOT A: L0.MFMA(t)  ||  L1.gates(t-2) ----------------
        if (!L1w) {
            if (t < TB) {
                const short8 a0 = *(const short8*)(lds16 + rdA);
                const short8 a1 = *(const short8*)(lds16 + rdA + 512);
                const int xaddr = (q == 0) ? (XBASE + ((t & 127) << 7) + ln8) : zaddr;
                const short8 a2 = *(const short8*)(lds16 + xaddr);
                ai0 = MFMA16(a0, Bf[0][0], biasv[0], 0, 0, 0);
                af0 = MFMA16(a0, Bf[1][0], biasv[1], 0, 0, 0);
                ag0 = MFMA16(a0, Bf[2][0], biasv[2], 0, 0, 0);
                ao0 = MFMA16(a0, Bf[3][0], biasv[3], 0, 0, 0);
                ai0 = MFMA16(a1, Bf[0][1], ai0, 0, 0, 0);
                af0 = MFMA16(a1, Bf[1][1], af0, 0, 0, 0);
                ag0 = MFMA16(a1, Bf[2][1], ag0, 0, 0, 0);
                ao0 = MFMA16(a1, Bf[3][1], ao0, 0, 0, 0);
                ai0 = MFMA16(a2, Bf[0][2], ai0, 0, 0, 0);
                af0 = MFMA16(a2, Bf[1][2], af0, 0, 0, 0);
                ag0 = MFMA16(a2, Bf[2][2], ag0, 0, 0, 0);
                ao0 = MFMA16(a2, Bf[3][2], ao0, 0, 0, 0);
            }
        } else {
            if (t >= 2) {                // finish step t-2: gates + write h1(t-2)
                unsigned hp[2];
                gates4(ai1, af1, ag1, ao1, cc, hp);
                lds16[wrH1]      = (unsigned short)hp[0];
                lds16[wrH1 + 8]  = (unsigned short)(hp[0] >> 16);
                lds16[wrH1 + 16] = (unsigned short)hp[1];
                lds16[wrH1 + 24] = (unsigned short)(hp[1] >> 16);
            }
        }
        if (ph == 62 && t + 2 < TB) {    // pack + write to the OTHER XB half
            const int t0 = (t & ~63) + 64;
            uint4 s0, s1;
            s0.x = pkbf(px0.x, px0.y); s0.y = pkbf(px0.z, px0.w);
            s0.z = pkbf(px1.x, px1.y); s0.w = pkbf(px1.z, px1.w);
            s1.x = pkbf(px2.x, px2.y); s1.y = pkbf(px2.z, px2.w);
            s1.z = pkbf(px3.x, px3.y); s1.w = pkbf(px3.z, px3.w);
            const int el = XBASE + ((t0 & 127) + su * 2) * 128 + srow * 8;
            *(uint4*)(lds16 + el)       = s0;
            *(uint4*)(lds16 + el + 128) = s1;
        }
        BAR();

        // ---------------- SLOT B: L0.gates(t)  ||  L1.MFMA(t-1) ----------------
        if (!L1w) {
            if (t < TB) {
                unsigned hp[2];
                gates4(ai0, af0, ag0, ao0, cc, hp);
                lds16[wr0]      = (unsigned short)hp[0];
                lds16[wr0 + 8]  = (unsigned short)(hp[0] >> 16);
                lds16[wr0 + 16] = (unsigned short)hp[1];
                lds16[wr0 + 24] = (unsigned short)(hp[1] >> 16);
            }
        } else {
            if (t >= 1 && t <= TB) {     // start step t-1: 16 MFMAs
                const short8 a0 = *(const short8*)(lds16 + rdA);        // h0(t-1) k 0..31
                const short8 a1 = *(const short8*)(lds16 + rdA + 512);  // h0(t-1) k 32..63
                const short8 b2 = *(const short8*)(lds16 + rdH1);       // h1(t-2) k 0..31
                const short8 b3 = *(const short8*)(lds16 + rdH1 + 512); // h1(t-2) k 32..63
                ai1 = MFMA16(a0, Bf[0][0], biasv[0], 0, 0, 0);
                af1 = MFMA16(a0, Bf[1][0], biasv[1], 0, 0, 0);
                ag1 = MFMA16(a0, Bf[2][0], biasv[2], 0, 0, 0);
                ao1 = MFMA16(a0, Bf[3][0], biasv[3], 0, 0, 0);
                ai1 = MFMA16(a1, Bf[0][1], ai1, 0, 0, 0);
                af1 = MFMA16(a1, Bf[1][1], af1, 0, 0, 0);
                ag1 = MFMA16(a1, Bf[2][1], ag1, 0, 0, 0);
                ao1 = MFMA16(a1, Bf[3][1], ao1, 0, 0, 0);
                ai1 = MFMA16(b2, Bf[0][2], ai1, 0, 0, 0);
                af1 = MFMA16(b2, Bf[1][2], af1, 0, 0, 0);
                ag1 = MFMA16(b2, Bf[2][2], ag1, 0, 0, 0);
                ao1 = MFMA16(b2, Bf[3][2], ao1, 0, 0, 0);
                ai1 = MFMA16(b3, Bf[0][3], ai1, 0, 0, 0);
                af1 = MFMA16(b3, Bf[1][3], af1, 0, 0, 0);
                ag1 = MFMA16(b3, Bf[2][3], ag1, 0, 0, 0);
                ao1 = MFMA16(b3, Bf[3][3], ao1, 0, 0, 0);
            }
        }
        BAR();
        rdA ^= A0TOG; wr0 ^= A0TOG; rdH1 ^= A1TOG; wrH1 ^= A1TOG;
    }

    // Final FC: h1(511) written at iter t=513 slot A, parity 1
    if (tid < BSL) {
        float s = bfc[0];
        #pragma unroll 8
        for (int j = 0; j < 64; ++j)
            s += bf2f(lds16[A1BASE + A1TOG + (j >> 3) * 128 + tid * 8 + (j & 7)]) * Wfc[j];
        out[rb + tid] = s;
    }
}

extern "C" void kernel_launch(void* const* d_in, const int* in_sizes, int n_in,
                              void* d_out, int out_size, void* d_ws, size_t ws_size,
                              hipStream_t stream) {
    const float* x    = (const float*)d_in[0];
    const float* Wih0 = (const float*)d_in[1];
    const float* Whh0 = (const float*)d_in[2];
    const float* bih0 = (const float*)d_in[3];
    const float* bhh0 = (const float*)d_in[4];
    const float* Wih1 = (const float*)d_in[5];
    const float* Whh1 = (const float*)d_in[6];
    const float* bih1 = (const float*)d_in[7];
    const float* bhh1 = (const float*)d_in[8];
    const float* Wfc  = (const float*)d_in[9];
    const float* bfc  = (const float*)d_in[10];
    float* out = (float*)d_out;

    dim3 grid(BTOT / BSL);   // 256 blocks = 1 per CU
    dim3 block(512);         // 8 waves: 4 L0 + 4 L1, staggered two-slot pipeline
    lstm2_fused<<<grid, block, 0, stream>>>(x, Wih0, Whh0, bih0, bhh0,
                                            Wih1, Whh1, bih1, bhh1, Wfc, bfc, out);
}

// Round 5
// 512.586 us; speedup vs baseline: 1.0995x; 1.0639x over previous
//
#include <hip/hip_runtime.h>

// Problem constants (fixed by the reference)
#define BTOT 4096
#define TB   512
#define BD   8
#define BSL  16    // MFMA tile M (BSL=8 duplicates wave-wide work chip-wide)

// LDS element map (uint16 elements, 2 B), k-major block layout:
//   A-tile element (row,k) at blk*128 + row*8 + (k&7), blk = k>>3
//   -> lane (q,ln)'s A-frag (row=ln, k=ki*32+q*8+j) = 16 contiguous bytes
//      at (ki*4+q)*128 + ln*8  => ds_read_b128, conflict-free per 8-lane group.
// A0 (h0, K=64): parity p at p*1024                      (els 0..2047)
// A1 (h1, K=64): parity p at 2048 + p*1024               (els 2048..4095)
// ZERO block (always 0, x-frag source for q>0 lanes):    (els 4096..4223)
// XB x chunks (64 t x 16 rows x 8 d, double-buffered):   (els 8192..24575)
#define A0TOG  1024
#define A1BASE 2048
#define A1TOG  1024
#define ZBASE  4096
#define XBASE  8192
#define NLDS   24576   // 48 KiB

typedef __attribute__((ext_vector_type(8))) short  short8;  // MFMA A/B frag
typedef __attribute__((ext_vector_type(4))) float  f32x4;   // MFMA C/D frag

#define MFMA16 __builtin_amdgcn_mfma_f32_16x16x32_bf16

// Raw barrier: wait only LDS ops (ds_write visibility), leave vmcnt
// outstanding so the ph48 global x-prefetch hides across ~14 barriers.
#define BAR() asm volatile("s_waitcnt lgkmcnt(0)\n\ts_barrier" ::: "memory")

static __device__ __forceinline__ unsigned short f2bf(float f) {
    unsigned u = __float_as_uint(f);
    u += 0x7fffu + ((u >> 16) & 1u);
    return (unsigned short)(u >> 16);
}
static __device__ __forceinline__ float bf2f(unsigned short h) {
    return __uint_as_float(((unsigned)h) << 16);
}
static __device__ __forceinline__ unsigned pkbf(float a, float b) {
    unsigned r;  // gfx950 HW packed f32->bf16 (RNE); dest must be VGPR
    asm("v_cvt_pk_bf16_f32 %0, %1, %2" : "=v"(r) : "v"(a), "v"(b));
    return r;
}

// One LSTM unit (one row of one lane's f32x4 accumulators).
// 7 trans/unit (5 exp2 + 2 rcp) — R3 proved plain v_rcp beats Newton
// fastrcp here (single issue slot; latency hidden by the 3 other rows).
// Pre-folded scales: i,f,o rows x -log2(e); g row x 2*log2(e).
//   c' = f*c + i*g = [c*Ai*Ag + Af*(eg-1)] / (Af*Ai*Ag)
//   h  = o*tanh(c') = (ec-1) / (Ao*(ec+1)),  ec = 2^(2*log2(e)*c')
static __device__ __forceinline__ float gate_row(
    float zi, float zf, float zg, float zo, float& c)
{
    const float ei = __builtin_amdgcn_exp2f(zi);
    const float ef = __builtin_amdgcn_exp2f(zf);
    const float eg = __builtin_amdgcn_exp2f(zg);
    const float eo = __builtin_amdgcn_exp2f(zo);
    const float Ai = 1.f + ei, Af = 1.f + ef, Ag = 1.f + eg, Ao = 1.f + eo;
    const float P     = Ai * Ag;
    const float numer = c * P + Af * (eg - 1.f);
    const float rD    = __builtin_amdgcn_rcpf(Af * P);
    c = numer * rD;
    const float ec = __builtin_amdgcn_exp2f(2.88539008f * c);
    const float rH = __builtin_amdgcn_rcpf(Ao * (ec + 1.f));
    return (ec - 1.f) * rH;
}

static __device__ __forceinline__ void gates4(
    const f32x4 ai, const f32x4 af, const f32x4 ag, const f32x4 ao,
    float cc[4], unsigned hp[2])
{
    float h[4];
    #pragma unroll
    for (int r = 0; r < 4; ++r)
        h[r] = gate_row(ai[r], af[r], ag[r], ao[r], cc[r]);
    hp[0] = pkbf(h[0], h[1]); hp[1] = pkbf(h[2], h[3]);
}

// MERGED-WAVE DESIGN, R2 ordering + plain rcp (this round): 4 waves/block,
// each wave owns 16 hidden cols for BOTH layers. Model (R0-R4): the SIMD
// serializes all pipe occupancy across waves (trans 16c, MFMA 16c, VALU 2c
// all additive) -> floor ~= 2100 cy/step. R2-R3 subtraction shows the
// reads-first + L1-MFMA/gates interleave is worth -24us on identical math.
__global__ __launch_bounds__(256, 1) void lstm2_fused(
    const float* __restrict__ x,
    const float* __restrict__ Wih0, const float* __restrict__ Whh0,
    const float* __restrict__ bih0, const float* __restrict__ bhh0,
    const float* __restrict__ Wih1, const float* __restrict__ Whh1,
    const float* __restrict__ bih1, const float* __restrict__ bhh1,
    const float* __restrict__ Wfc,  const float* __restrict__ bfc,
    float* __restrict__ out)
{
    __shared__ __align__(16) unsigned short lds16[NLDS];

    const int tid  = threadIdx.x;
    const int wid  = tid >> 6;           // 4 waves; wave g = cols 16g..16g+15
    const int lane = tid & 63;
    const int q    = lane >> 4;
    const int ln   = lane & 15;
    const int rb   = blockIdx.x * BSL;
    const int jc   = wid * 16 + ln;      // hidden col this lane owns (both layers)

    const float SCI = -1.44269504f;
    const float SCG =  2.88539008f;

    // ---- Weight fragments -> registers (both layers), bf16, scales folded ----
    short8 Bf0[4][3];                    // L0: k 0..63 = Whh0, 64..71 = Wih0
    short8 Bf1[4][4];                    // L1: k 0..63 = Wih1, 64..127 = Whh1
    #pragma unroll
    for (int G = 0; G < 4; ++G) {
        const int n = G * 64 + jc;
        const float sc = (G == 2) ? SCG : SCI;
        #pragma unroll
        for (int ki = 0; ki < 3; ++ki) {
            union { unsigned short u[8]; short8 v; } t;
            #pragma unroll
            for (int j = 0; j < 8; ++j) {
                const int k = ki * 32 + q * 8 + j;
                float wv = 0.0f;
                if (k < 64)      wv = Whh0[n * 64 + k];
                else if (k < 72) wv = Wih0[n * 8 + (k - 64)];
                t.u[j] = f2bf(sc * wv);
            }
            Bf0[G][ki] = t.v;
        }
        #pragma unroll
        for (int ki = 0; ki < 4; ++ki) {
            union { unsigned short u[8]; short8 v; } t;
            #pragma unroll
            for (int j = 0; j < 8; ++j) {
                const int k = ki * 32 + q * 8 + j;
                const float wv = (k < 64) ? Wih1[n * 64 + k]
                                          : Whh1[n * 64 + (k - 64)];
                t.u[j] = f2bf(sc * wv);
            }
            Bf1[G][ki] = t.v;
        }
    }
    f32x4 bias0[4], bias1[4];            // bias as persistent MFMA C-operand
    #pragma unroll
    for (int G = 0; G < 4; ++G) {
        const int n = G * 64 + jc;
        const float sc = (G == 2) ? SCG : SCI;
        const float b0 = sc * (bih0[n] + bhh0[n]);
        const float b1 = sc * (bih1[n] + bhh1[n]);
        bias0[G] = (f32x4){b0, b0, b0, b0};
        bias1[G] = (f32x4){b1, b1, b1, b1};
    }

    // ---- Prologue: zero A0/A1/ZERO, stage x chunk 0 ----
    {
        unsigned* z = (unsigned*)lds16;   // els 0..4223 = 2112 dwords
        #pragma unroll
        for (int i = 0; i < 9; ++i) {
            const int id = tid + i * 256;
            if (id < 2112) z[id] = 0;
        }
    }
    const int srow = tid >> 4, su = tid & 15;  // stager: 32 floats/thread
    {
        const float* gp = x + (size_t)(rb + srow) * (TB * BD) + su * 32;
        float4 v[8];
        #pragma unroll
        for (int i = 0; i < 8; ++i) v[i] = ((const float4*)gp)[i];
        #pragma unroll
        for (int tt = 0; tt < 4; ++tt) {
            uint4 s;
            s.x = pkbf(v[2*tt].x,   v[2*tt].y);   s.y = pkbf(v[2*tt].z,   v[2*tt].w);
            s.z = pkbf(v[2*tt+1].x, v[2*tt+1].y); s.w = pkbf(v[2*tt+1].z, v[2*tt+1].w);
            const int el = XBASE + (su * 4 + tt) * 128 + srow * 8;
            *(uint4*)(lds16 + el) = s;
        }
    }
    __syncthreads();

    // ---- Hoisted ping-pong pointers (element indices), XOR-toggled ----
    const int rbase = q * 128 + ln * 8;                    // A-frag read base
    const int wb    = (jc >> 3) * 128 + q * 32 + (jc & 7); // h-write base
    const int ln8   = ln * 8;
    const int zaddr = ZBASE + ln8;       // q>0 x-frag source (always zero)
    int rdA  = rbase;                    // h0(t-1): read by BOTH layers
    int wr0  = A0TOG + wb;               // h0(t) -> other parity
    int rdH1 = A1BASE + rbase;           // h1(t1-1)
    int wrH1 = A1BASE + A1TOG + wb;      // h1(t1) -> other parity

    float cc0[4] = {0.f, 0.f, 0.f, 0.f};
    float cc1[4] = {0.f, 0.f, 0.f, 0.f};
    float4 px[8];                        // x-chunk global prefetch registers

    // ---- Peeled it=0: L0 only (h0(-1)=h1(-1)=0) ----
    {
        const short8 a0 = *(const short8*)(lds16 + rdA);
        const short8 a1 = *(const short8*)(lds16 + rdA + 512);
        const int xaddr = (q == 0) ? (XBASE + 0 + ln8) : zaddr;
        const short8 a2 = *(const short8*)(lds16 + xaddr);
        f32x4 ai = MFMA16(a0, Bf0[0][0], bias0[0], 0, 0, 0);
        f32x4 af = MFMA16(a0, Bf0[1][0], bias0[1], 0, 0, 0);
        f32x4 ag = MFMA16(a0, Bf0[2][0], bias0[2], 0, 0, 0);
        f32x4 ao = MFMA16(a0, Bf0[3][0], bias0[3], 0, 0, 0);
        ai = MFMA16(a1, Bf0[0][1], ai, 0, 0, 0);
        af = MFMA16(a1, Bf0[1][1], af, 0, 0, 0);
        ag = MFMA16(a1, Bf0[2][1], ag, 0, 0, 0);
        ao = MFMA16(a1, Bf0[3][1], ao, 0, 0, 0);
        ai = MFMA16(a2, Bf0[0][2], ai, 0, 0, 0);
        af = MFMA16(a2, Bf0[1][2], af, 0, 0, 0);
        ag = MFMA16(a2, Bf0[2][2], ag, 0, 0, 0);
        ao = MFMA16(a2, Bf0[3][2], ao, 0, 0, 0);
        unsigned hp[2];
        gates4(ai, af, ag, ao, cc0, hp);
        lds16[wr0]      = (unsigned short)hp[0];
        lds16[wr0 + 8]  = (unsigned short)(hp[0] >> 16);
        lds16[wr0 + 16] = (unsigned short)hp[1];
        lds16[wr0 + 24] = (unsigned short)(hp[1] >> 16);
        BAR();
        rdA ^= A0TOG; wr0 ^= A0TOG; rdH1 ^= A1TOG; wrH1 ^= A1TOG;
    }

    // ---- Steady state it=1..TB-1: reads first, interleaved pipes ----
    for (int it = 1; it < TB; ++it) {
        const int ph = it & 63;
        // Shared reads first (post-barrier critical path): h0(it-1) feeds
        // L0 recurrence AND L1 input; h1(it-2) feeds L1 recurrence.
        const short8 a0 = *(const short8*)(lds16 + rdA);
        const short8 a1 = *(const short8*)(lds16 + rdA + 512);
        const short8 b2 = *(const short8*)(lds16 + rdH1);        // h1 k 0..31
        const short8 b3 = *(const short8*)(lds16 + rdH1 + 512);  // h1 k 32..63
        const int xaddr = (q == 0) ? (XBASE + ((it & 127) << 7) + ln8) : zaddr;
        const short8 a2 = *(const short8*)(lds16 + xaddr);

        if (ph == 48 && it + 16 < TB) {  // prefetch next chunk -> regs
            const int t0 = (it & ~63) + 64;
            const float* gp = x + (size_t)(rb + srow) * (TB * BD) + t0 * BD + su * 32;
            #pragma unroll
            for (int i = 0; i < 8; ++i) px[i] = ((const float4*)gp)[i];
        }
        if (ph == 62 && it + 2 < TB) {   // pack + write to OTHER XB buffer
            const int t0 = (it & ~63) + 64;
            #pragma unroll
            for (int tt = 0; tt < 4; ++tt) {
                uint4 s;
                s.x = pkbf(px[2*tt].x,   px[2*tt].y);   s.y = pkbf(px[2*tt].z,   px[2*tt].w);
                s.z = pkbf(px[2*tt+1].x, px[2*tt+1].y); s.w = pkbf(px[2*tt+1].z, px[2*tt+1].w);
                const int el = XBASE + ((t0 + su * 4 + tt) & 127) * 128 + srow * 8;
                *(uint4*)(lds16 + el) = s;
            }
        }

        // L0 MFMAs (step t = it) — gates0 needs all 12 complete
        f32x4 ai0 = MFMA16(a0, Bf0[0][0], bias0[0], 0, 0, 0);
        f32x4 af0 = MFMA16(a0, Bf0[1][0], bias0[1], 0, 0, 0);
        f32x4 ag0 = MFMA16(a0, Bf0[2][0], bias0[2], 0, 0, 0);
        f32x4 ao0 = MFMA16(a0, Bf0[3][0], bias0[3], 0, 0, 0);
        ai0 = MFMA16(a1, Bf0[0][1], ai0, 0, 0, 0);
        af0 = MFMA16(a1, Bf0[1][1], af0, 0, 0, 0);
        ag0 = MFMA16(a1, Bf0[2][1], ag0, 0, 0, 0);
        ao0 = MFMA16(a1, Bf0[3][1], ao0, 0, 0, 0);
        ai0 = MFMA16(a2, Bf0[0][2], ai0, 0, 0, 0);
        af0 = MFMA16(a2, Bf0[1][2], af0, 0, 0, 0);
        ag0 = MFMA16(a2, Bf0[2][2], ag0, 0, 0, 0);
        ao0 = MFMA16(a2, Bf0[3][2], ao0, 0, 0, 0);

        // INTERLEAVE: {4 L1 MFMAs on frag k ; gates0 row k} x4.
        // gates0 rows depend only on completed L0 accumulators; L1 MFMAs
        // depend only on a0/a1/b2/b3 -> matrix pipe runs under trans pipe.
        float h00, h01, h02, h03;
        f32x4 ai1 = MFMA16(a0, Bf1[0][0], bias1[0], 0, 0, 0);
        f32x4 af1 = MFMA16(a0, Bf1[1][0], bias1[1], 0, 0, 0);
        f32x4 ag1 = MFMA16(a0, Bf1[2][0], bias1[2], 0, 0, 0);
        f32x4 ao1 = MFMA16(a0, Bf1[3][0], bias1[3], 0, 0, 0);
        h00 = gate_row(ai0[0], af0[0], ag0[0], ao0[0], cc0[0]);
        ai1 = MFMA16(a1, Bf1[0][1], ai1, 0, 0, 0);
        af1 = MFMA16(a1, Bf1[1][1], af1, 0, 0, 0);
        ag1 = MFMA16(a1, Bf1[2][1], ag1, 0, 0, 0);
        ao1 = MFMA16(a1, Bf1[3][1], ao1, 0, 0, 0);
        h01 = gate_row(ai0[1], af0[1], ag0[1], ao0[1], cc0[1]);
        ai1 = MFMA16(b2, Bf1[0][2], ai1, 0, 0, 0);
        af1 = MFMA16(b2, Bf1[1][2], af1, 0, 0, 0);
        ag1 = MFMA16(b2, Bf1[2][2], ag1, 0, 0, 0);
        ao1 = MFMA16(b2, Bf1[3][2], ao1, 0, 0, 0);
        h02 = gate_row(ai0[2], af0[2], ag0[2], ao0[2], cc0[2]);
        ai1 = MFMA16(b3, Bf1[0][3], ai1, 0, 0, 0);
        af1 = MFMA16(b3, Bf1[1][3], af1, 0, 0, 0);
        ag1 = MFMA16(b3, Bf1[2][3], ag1, 0, 0, 0);
        ao1 = MFMA16(b3, Bf1[3][3], ao1, 0, 0, 0);
        h03 = gate_row(ai0[3], af0[3], ag0[3], ao0[3], cc0[3]);

        const unsigned p00 = pkbf(h00, h01), p01 = pkbf(h02, h03);
        lds16[wr0]      = (unsigned short)p00;
        lds16[wr0 + 8]  = (unsigned short)(p00 >> 16);
        lds16[wr0 + 16] = (unsigned short)p01;
        lds16[wr0 + 24] = (unsigned short)(p01 >> 16);

        unsigned hp1[2];
        gates4(ai1, af1, ag1, ao1, cc1, hp1);
        lds16[wrH1]      = (unsigned short)hp1[0];
        lds16[wrH1 + 8]  = (unsigned short)(hp1[0] >> 16);
        lds16[wrH1 + 16] = (unsigned short)hp1[1];
        lds16[wrH1 + 24] = (unsigned short)(hp1[1] >> 16);

        BAR();
        rdA ^= A0TOG; wr0 ^= A0TOG; rdH1 ^= A1TOG; wrH1 ^= A1TOG;
    }

    // ---- Peeled it=TB: L1 only (step t1 = TB-1) ----
    {
        const short8 a0 = *(const short8*)(lds16 + rdA);
        const short8 a1 = *(const short8*)(lds16 + rdA + 512);
        const short8 b2 = *(const short8*)(lds16 + rdH1);
        const short8 b3 = *(const short8*)(lds16 + rdH1 + 512);
        f32x4 ai = MFMA16(a0, Bf1[0][0], bias1[0], 0, 0, 0);
        f32x4 af = MFMA16(a0, Bf1[1][0], bias1[1], 0, 0, 0);
        f32x4 ag = MFMA16(a0, Bf1[2][0], bias1[2], 0, 0, 0);
        f32x4 ao = MFMA16(a0, Bf1[3][0], bias1[3], 0, 0, 0);
        ai = MFMA16(a1, Bf1[0][1], ai, 0, 0, 0);
        af = MFMA16(a1, Bf1[1][1], af, 0, 0, 0);
        ag = MFMA16(a1, Bf1[2][1], ag, 0, 0, 0);
        ao = MFMA16(a1, Bf1[3][1], ao, 0, 0, 0);
        ai = MFMA16(b2, Bf1[0][2], ai, 0, 0, 0);
        af = MFMA16(b2, Bf1[1][2], af, 0, 0, 0);
        ag = MFMA16(b2, Bf1[2][2], ag, 0, 0, 0);
        ao = MFMA16(b2, Bf1[3][2], ao, 0, 0, 0);
        ai = MFMA16(b3, Bf1[0][3], ai, 0, 0, 0);
        af = MFMA16(b3, Bf1[1][3], af, 0, 0, 0);
        ag = MFMA16(b3, Bf1[2][3], ag, 0, 0, 0);
        ao = MFMA16(b3, Bf1[3][3], ao, 0, 0, 0);
        unsigned hp[2];
        gates4(ai, af, ag, ao, cc1, hp);
        lds16[wrH1]      = (unsigned short)hp[0];
        lds16[wrH1 + 8]  = (unsigned short)(hp[0] >> 16);
        lds16[wrH1 + 16] = (unsigned short)hp[1];
        lds16[wrH1 + 24] = (unsigned short)(hp[1] >> 16);
        BAR();
    }

    // Final FC: h1(511) written at it=512 -> A1 parity 1
    if (tid < BSL) {
        float s = bfc[0];
        #pragma unroll 8
        for (int j = 0; j < 64; ++j)
            s += bf2f(lds16[A1BASE + A1TOG + (j >> 3) * 128 + tid * 8 + (j & 7)]) * Wfc[j];
        out[rb + tid] = s;
    }
}

extern "C" void kernel_launch(void* const* d_in, const int* in_sizes, int n_in,
                              void* d_out, int out_size, void* d_ws, size_t ws_size,
                              hipStream_t stream) {
    const float* x    = (const float*)d_in[0];
    const float* Wih0 = (const float*)d_in[1];
    const float* Whh0 = (const float*)d_in[2];
    const float* bih0 = (const float*)d_in[3];
    const float* bhh0 = (const float*)d_in[4];
    const float* Wih1 = (const float*)d_in[5];
    const float* Whh1 = (const float*)d_in[6];
    const float* bih1 = (const float*)d_in[7];
    const float* bhh1 = (const float*)d_in[8];
    const float* Wfc  = (const float*)d_in[9];
    const float* bfc  = (const float*)d_in[10];
    float* out = (float*)d_out;

    dim3 grid(BTOT / BSL);   // 256 blocks = 1 per CU
    dim3 block(256);         // 4 waves: each owns 16 hidden cols, BOTH layers
    lstm2_fused<<<grid, block, 0, stream>>>(x, Wih0, Whh0, bih0, bhh0,
                                            Wih1, Whh1, bih1, bhh1, Wfc, bfc, out);
}